// Round 6
// baseline (23.906 us; speedup 1.0000x reference)
//
#include <hip/hip_runtime.h>

#define BINS 32
#define OUT_PER_ROW (BINS * BINS * BINS)   // 32768
#define WORDS (OUT_PER_ROW / 2)            // 16384 packed u32 (2 x u16 counts) per row
#define THREADS 1024

typedef float vfloat4 __attribute__((ext_vector_type(4)));   // native vec for nontemporal store

// Exact slow path: idx = #{ edges[j] < x : j in [1, BINS-1] }
// (== searchsorted(edges[1:-1], x, 'left')). Arithmetic guess (within +-1 for
// these near-uniform edges) + one-step fixup against ACTUAL edge values.
__device__ __forceinline__ int bucket_exact(float x, const float* __restrict__ se,
                                            float e0, float scale) {
    float t = fminf(fmaxf((x - e0) * scale, 0.0f), (float)(BINS - 1));
    int i = (int)t;
    const float f0 = se[i];
    const float f1 = se[i + 1];
    const int up = (int)(i < BINS - 1) & (int)(f1 < x);
    i += up;
    const float fi = up ? f1 : f0;           // == se[i] at the new i
    i -= (int)(i > 0) & (int)(fi >= x);
    return i;
}

// Fast path: pure-arithmetic bin, provably exact whenever t=(x-e0)*scale is
// farther than eps from every internal integer edge index. eps is derived at
// runtime from the ACTUAL edge values, so exactness is guaranteed (no linspace
// rounding assumption). Whole-wave fallback only if any lane is near an edge.
__device__ __forceinline__ int bucket(float x, const float* __restrict__ se,
                                      float e0, float scale, float eps) {
    const float t = (x - e0) * scale;
    const float rt = rintf(t);
    const bool near_edge = (fabsf(t - rt) <= eps) & (rt >= 1.0f) & (rt <= 31.0f);
    if (__builtin_expect(__ballot((int)near_edge) != 0ull, 0)) {
        return bucket_exact(x, se, e0, scale);   // wave-uniform, exact
    }
    return min(max((int)floorf(t), 0), BINS - 1);
}

__device__ __forceinline__ void bin_group(const float4& a, const float4& c,
                                          const float4& d,
                                          const float* __restrict__ se,
                                          float e0, float scale, float eps,
                                          unsigned int* __restrict__ hist) {
    const int l0 = bucket(a.x, se, e0, scale, eps)
                 + BINS * bucket(a.y, se, e0, scale, eps)
                 + BINS * BINS * bucket(a.z, se, e0, scale, eps);
    const int l1 = bucket(a.w, se, e0, scale, eps)
                 + BINS * bucket(c.x, se, e0, scale, eps)
                 + BINS * BINS * bucket(c.y, se, e0, scale, eps);
    const int l2 = bucket(c.z, se, e0, scale, eps)
                 + BINS * bucket(c.w, se, e0, scale, eps)
                 + BINS * BINS * bucket(d.x, se, e0, scale, eps);
    const int l3 = bucket(d.y, se, e0, scale, eps)
                 + BINS * bucket(d.z, se, e0, scale, eps)
                 + BINS * BINS * bucket(d.w, se, e0, scale, eps);
    // packed u16 pair per u32 word; counts <= N=8192 so no carry-over
    atomicAdd(&hist[l0 >> 1], 1u << ((l0 & 1) << 4));
    atomicAdd(&hist[l1 >> 1], 1u << ((l1 & 1) << 4));
    atomicAdd(&hist[l2 >> 1], 1u << ((l2 & 1) << 4));
    atomicAdd(&hist[l3 >> 1], 1u << ((l3 & 1) << 4));
}

__device__ __forceinline__ void write_row(const unsigned int* __restrict__ hist,
                                          float* __restrict__ orow_f, float invn,
                                          int tid) {
    vfloat4* orow = reinterpret_cast<vfloat4*>(orow_f);
    const uint2* h2 = reinterpret_cast<const uint2*>(hist);
#pragma unroll
    for (int j = 0; j < OUT_PER_ROW / 4 / THREADS; ++j) {
        const int m = tid + j * THREADS;
        const uint2 w = h2[m];
        vfloat4 v;
        v.x = (float)(w.x & 0xFFFFu) * invn;
        v.y = (float)(w.x >> 16) * invn;
        v.z = (float)(w.y & 0xFFFFu) * invn;
        v.w = (float)(w.y >> 16) * invn;
        __builtin_nontemporal_store(v, &orow[m]);   // streaming, never re-read
    }
}

// Two rows per block, software-pipelined: row1 loads overlap row0 epilogue
// stores so HBM read and write streams run concurrently instead of in
// serialized phases. 128 KiB LDS -> 1 block/CU, 16 waves/CU.
__global__ __launch_bounds__(THREADS, 4)
void bin_density_kernel(const float* __restrict__ states,
                        const float* __restrict__ edges,
                        float* __restrict__ out, int N) {
    __shared__ unsigned int hist0[WORDS];   // 64 KiB
    __shared__ unsigned int hist1[WORDS];   // 64 KiB
    __shared__ float se[BINS + 1];

    const int tid = threadIdx.x;
    const int b = blockIdx.x;               // rows 2b and 2b+1
    const long long rowf = (long long)N * 3;

    const float4* sp0 = reinterpret_cast<const float4*>(states + 2 * b * rowf);
    const float4* sp1 = reinterpret_cast<const float4*>(states + (2 * b + 1) * rowf);

    // N=8192 -> 2048 groups of 4 samples; exactly 2 groups per thread.
    const int g0 = tid;
    const int g1 = tid + THREADS;

    // Prefetch row0 into registers BEFORE zeroing (hides zero phase + latency).
    const float4 a0 = sp0[3 * g0 + 0], c0 = sp0[3 * g0 + 1], d0 = sp0[3 * g0 + 2];
    const float4 a1 = sp0[3 * g1 + 0], c1 = sp0[3 * g1 + 1], d1 = sp0[3 * g1 + 2];

    if (tid < BINS + 1) se[tid] = edges[tid];

    uint4* h40 = reinterpret_cast<uint4*>(hist0);
    uint4* h41 = reinterpret_cast<uint4*>(hist1);
#pragma unroll
    for (int j = 0; j < WORDS / 4 / THREADS; ++j) {
        h40[tid + j * THREADS] = uint4{0u, 0u, 0u, 0u};
        h41[tid + j * THREADS] = uint4{0u, 0u, 0u, 0u};
    }
    __syncthreads();

    const float e0 = se[0];
    const float scale = (float)BINS / (se[BINS] - e0);
    float dmax = 0.0f;
#pragma unroll
    for (int k = 1; k < BINS; ++k)
        dmax = fmaxf(dmax, fabsf((se[k] - e0) * scale - (float)k));
    const float eps = dmax * 1.01f + 3e-5f;
    const float invn = 1.0f / (float)N;

    // ---- bin row 0 ----
    bin_group(a0, c0, d0, se, e0, scale, eps, hist0);
    bin_group(a1, c1, d1, se, e0, scale, eps, hist0);
    __syncthreads();

    // ---- overlapped phase: issue row1 loads, write row0, bin row1 ----
    const float4 A0 = sp1[3 * g0 + 0], C0 = sp1[3 * g0 + 1], D0 = sp1[3 * g0 + 2];
    const float4 A1 = sp1[3 * g1 + 0], C1 = sp1[3 * g1 + 1], D1 = sp1[3 * g1 + 2];

    write_row(hist0, out + (long long)(2 * b) * OUT_PER_ROW, invn, tid);

    bin_group(A0, C0, D0, se, e0, scale, eps, hist1);
    bin_group(A1, C1, D1, se, e0, scale, eps, hist1);
    __syncthreads();

    // ---- write row 1 ----
    write_row(hist1, out + (long long)(2 * b + 1) * OUT_PER_ROW, invn, tid);
}

extern "C" void kernel_launch(void* const* d_in, const int* in_sizes, int n_in,
                              void* d_out, int out_size, void* d_ws, size_t ws_size,
                              hipStream_t stream) {
    const float* states = (const float*)d_in[0];
    const float* edges = (const float*)d_in[1];
    float* out = (float*)d_out;

    const int B = out_size / OUT_PER_ROW;          // 512
    const int N = in_sizes[0] / (3 * B);           // 8192

    bin_density_kernel<<<B / 2, THREADS, 0, stream>>>(states, edges, out, N);
}

// Round 7
// 22.520 us; speedup vs baseline: 1.0616x; 1.0616x over previous
//
#include <hip/hip_runtime.h>

#define BINS 32
#define OUT_PER_ROW (BINS * BINS * BINS)   // 32768
#define WORDS (OUT_PER_ROW / 2)            // 16384 packed u32 (2 x u16 counts)
#define THREADS 1024

typedef float vfloat4 __attribute__((ext_vector_type(4)));   // native vec for nontemporal store

// Exact slow path: idx = #{ edges[j] < x : j in [1, BINS-1] }
// (== searchsorted(edges[1:-1], x, 'left')). Arithmetic guess (within +-1 for
// these near-uniform edges) + one-step fixup against ACTUAL edge values.
__device__ __forceinline__ int bucket_exact(float x, const float* __restrict__ se,
                                            float e0, float scale) {
    float t = fminf(fmaxf((x - e0) * scale, 0.0f), (float)(BINS - 1));
    int i = (int)t;
    const float f0 = se[i];
    const float f1 = se[i + 1];
    const int up = (int)(i < BINS - 1) & (int)(f1 < x);
    i += up;
    const float fi = up ? f1 : f0;           // == se[i] at the new i
    i -= (int)(i > 0) & (int)(fi >= x);
    return i;
}

// Fast path: pure-arithmetic bin, provably exact whenever t=(x-e0)*scale is
// farther than eps from every internal integer edge index. eps is derived at
// runtime from the ACTUAL edge values (no linspace-rounding assumption), so
// exactness is guaranteed. Whole-wave fallback only if any lane is near an
// edge (probability ~1e-4 per bucket).
__device__ __forceinline__ int bucket(float x, const float* __restrict__ se,
                                      float e0, float scale, float eps) {
    const float t = (x - e0) * scale;
    const float rt = rintf(t);
    const bool near_edge = (fabsf(t - rt) <= eps) & (rt >= 1.0f) & (rt <= 31.0f);
    if (__builtin_expect(__ballot((int)near_edge) != 0ull, 0)) {
        return bucket_exact(x, se, e0, scale);   // wave-uniform, exact
    }
    return min(max((int)floorf(t), 0), BINS - 1);
}

__device__ __forceinline__ void bin_group(const float4& a, const float4& c,
                                          const float4& d,
                                          const float* __restrict__ se,
                                          float e0, float scale, float eps,
                                          unsigned int* __restrict__ hist) {
    const int l0 = bucket(a.x, se, e0, scale, eps)
                 + BINS * bucket(a.y, se, e0, scale, eps)
                 + BINS * BINS * bucket(a.z, se, e0, scale, eps);
    const int l1 = bucket(a.w, se, e0, scale, eps)
                 + BINS * bucket(c.x, se, e0, scale, eps)
                 + BINS * BINS * bucket(c.y, se, e0, scale, eps);
    const int l2 = bucket(c.z, se, e0, scale, eps)
                 + BINS * bucket(c.w, se, e0, scale, eps)
                 + BINS * BINS * bucket(d.x, se, e0, scale, eps);
    const int l3 = bucket(d.y, se, e0, scale, eps)
                 + BINS * bucket(d.z, se, e0, scale, eps)
                 + BINS * BINS * bucket(d.w, se, e0, scale, eps);
    // packed u16 pair per u32 word; counts <= N=8192 so no carry-over
    atomicAdd(&hist[l0 >> 1], 1u << ((l0 & 1) << 4));
    atomicAdd(&hist[l1 >> 1], 1u << ((l1 & 1) << 4));
    atomicAdd(&hist[l2 >> 1], 1u << ((l2 & 1) << 4));
    atomicAdd(&hist[l3 >> 1], 1u << ((l3 & 1) << 4));
}

// 8 waves/SIMD: VGPR <= 64 so the LDS-allowed 2 blocks/CU (32 waves/CU)
// is actually reached. 64 KiB hist -> 2 blocks/CU.
__global__ __launch_bounds__(THREADS, 8)
void bin_density_kernel(const float* __restrict__ states,
                        const float* __restrict__ edges,
                        float* __restrict__ out, int N) {
    __shared__ unsigned int hist[WORDS];   // 64 KiB
    __shared__ float se[BINS + 1];

    const int tid = threadIdx.x;
    const int b = blockIdx.x;

    const float4* sp4 = reinterpret_cast<const float4*>(states + (long long)b * N * 3);
    const int g0 = tid;
    const int g1 = tid + THREADS;          // N=8192 -> 2048 groups, 2/thread

    // Prefetch group 0 BEFORE zeroing: its ~900-cycle HBM latency hides
    // under the 64 KiB LDS zero + barrier instead of serializing after it.
    const float4 a0 = sp4[3 * g0 + 0];
    const float4 c0 = sp4[3 * g0 + 1];
    const float4 d0 = sp4[3 * g0 + 2];

    if (tid < BINS + 1) se[tid] = edges[tid];

    uint4* h4 = reinterpret_cast<uint4*>(hist);
#pragma unroll
    for (int j = 0; j < WORDS / 4 / THREADS; ++j)
        h4[tid + j * THREADS] = uint4{0u, 0u, 0u, 0u};

    __syncthreads();

    // Issue group-1 loads now; latency hides under group-0 binning compute.
    const float4 a1 = sp4[3 * g1 + 0];
    const float4 c1 = sp4[3 * g1 + 1];
    const float4 d1 = sp4[3 * g1 + 2];

    const float e0 = se[0];
    const float scale = (float)BINS / (se[BINS] - e0);
    float dmax = 0.0f;
#pragma unroll
    for (int k = 1; k < BINS; ++k)
        dmax = fmaxf(dmax, fabsf((se[k] - e0) * scale - (float)k));
    const float eps = dmax * 1.01f + 3e-5f;

    bin_group(a0, c0, d0, se, e0, scale, eps, hist);
    bin_group(a1, c1, d1, se, e0, scale, eps, hist);

    __syncthreads();

    // Epilogue: 2 packed words -> float4, lane-coalesced 16B nontemporal
    // stores (output is never re-read; keep L3 capacity for states).
    const float invn = 1.0f / (float)N;
    vfloat4* orow = reinterpret_cast<vfloat4*>(out + (long long)b * OUT_PER_ROW);
    const uint2* h2 = reinterpret_cast<const uint2*>(hist);
#pragma unroll
    for (int j = 0; j < OUT_PER_ROW / 4 / THREADS; ++j) {
        const int m = tid + j * THREADS;
        const uint2 w = h2[m];
        vfloat4 v;
        v.x = (float)(w.x & 0xFFFFu) * invn;
        v.y = (float)(w.x >> 16) * invn;
        v.z = (float)(w.y & 0xFFFFu) * invn;
        v.w = (float)(w.y >> 16) * invn;
        __builtin_nontemporal_store(v, &orow[m]);
    }
}

extern "C" void kernel_launch(void* const* d_in, const int* in_sizes, int n_in,
                              void* d_out, int out_size, void* d_ws, size_t ws_size,
                              hipStream_t stream) {
    const float* states = (const float*)d_in[0];
    const float* edges = (const float*)d_in[1];
    float* out = (float*)d_out;

    const int B = out_size / OUT_PER_ROW;          // 512
    const int N = in_sizes[0] / (3 * B);           // 8192

    bin_density_kernel<<<B, THREADS, 0, stream>>>(states, edges, out, N);
}